// Round 7
// baseline (287.952 us; speedup 1.0000x reference)
//
#include <hip/hip_runtime.h>
#include <math.h>

#define NU_F 0.0031830988618379067f
#define HS 136   // halves per H row: 17*8 -> 16B-aligned, odd 16B-stride = bank-balanced

typedef __attribute__((ext_vector_type(8))) _Float16 half8;
typedef __attribute__((ext_vector_type(16))) float f32x16;

__device__ __forceinline__ float fast_tanh(float x) {
    const float e = __expf(2.f * x);
    return 1.f - 2.f / (e + 1.f);
}

// ---------------------------------------------------------------------------
// Weight prep: W[l][k][n] fp32 -> k-tiled fp16 hi/lo:
//   idx = l*16384 + (k>>4)*2048 + n*16 + (k&15)
// so a wave's per-kt B-read (n-contiguous, 16 halves each) is one 1KB block.
// ---------------------------------------------------------------------------
__global__ void prep_kernel(const float* __restrict__ W1,
                            const float* __restrict__ W2,
                            const float* __restrict__ W3,
                            _Float16* __restrict__ ws)
{
    const int g = blockIdx.x * 256 + threadIdx.x;   // 0..49151
    const int l = g >> 14;
    const int r = g & 16383;
    const int n = r & 127;
    const int k = r >> 7;
    const float* W = (l == 0) ? W1 : (l == 1) ? W2 : W3;
    const float w = W[k * 128 + n];
    const _Float16 hi = (_Float16)w;
    const _Float16 lo = (_Float16)(w - (float)hi);
    const int idx = l * 16384 + (k >> 4) * 2048 + n * 16 + (k & 15);
    ws[idx]         = hi;
    ws[49152 + idx] = lo;
}

// One epilogue group: rows mt*32+8g+4*khalf+{0..3} of set E from acc regs
// (C-layout: reg&3 = row-within-4 = derivative channel for eq blocks).
template<bool IS_EQ>
__device__ __forceinline__ void egroup(int grp, const f32x16 (&accE)[2],
                                       _Float16 (*EHhi)[HS], _Float16 (*EHlo)[HS],
                                       float bias, int khalf, int ncol)
{
    const int mt = grp >> 2, g = grp & 3;
    const int mrow0 = mt * 32 + 8 * g + 4 * khalf;
    const float A0 = accE[mt][4 * g + 0];
    const float A1 = accE[mt][4 * g + 1];
    const float A2 = accE[mt][4 * g + 2];
    const float A3 = accE[mt][4 * g + 3];
    float h[4];
    if (IS_EQ) {
        const float a = fast_tanh(A0 + bias);
        const float s = 1.f - a * a;
        h[0] = a;
        h[1] = s * A1;
        h[2] = s * A2;
        h[3] = fmaf(s, A3, -2.f * a * s * A2 * A2);
    } else {
        h[0] = fast_tanh(A0 + bias);
        h[1] = fast_tanh(A1 + bias);
        h[2] = fast_tanh(A2 + bias);
        h[3] = fast_tanh(A3 + bias);
    }
    #pragma unroll
    for (int c = 0; c < 4; ++c) {
        const _Float16 hi = (_Float16)h[c];
        EHhi[mrow0 + c][ncol] = hi;
        EHlo[mrow0 + c][ncol] = (_Float16)(h[c] - (float)hi);
    }
}

// One phase: K-loop (3-term split-fp16 MFMA) on set K at `ph/pl` weights,
// interleaved with the epilogue of set E (acc from the previous phase).
template<bool IS_EQ, bool DO_E>
__device__ __forceinline__ void kphase(const _Float16* __restrict__ ph,
                                       const _Float16* __restrict__ pl,
                                       const _Float16 (*KHhi)[HS],
                                       const _Float16 (*KHlo)[HS],
                                       f32x16 (&accK)[2],
                                       const f32x16 (&accE)[2],
                                       _Float16 (*EHhi)[HS], _Float16 (*EHlo)[HS],
                                       float bias, int col, int khalf, int ncol)
{
    #pragma unroll
    for (int mt = 0; mt < 2; ++mt)
        #pragma unroll
        for (int e = 0; e < 16; ++e) accK[mt][e] = 0.f;

    half8 bh[2], bl[2];
    bh[0] = *(const half8*)(ph);         bl[0] = *(const half8*)(pl);
    bh[1] = *(const half8*)(ph + 2048);  bl[1] = *(const half8*)(pl + 2048);

    #pragma unroll
    for (int kt = 0; kt < 8; ++kt) {
        half8 nbh, nbl;
        if (kt < 6) {
            nbh = *(const half8*)(ph + (kt + 2) * 2048);
            nbl = *(const half8*)(pl + (kt + 2) * 2048);
        }
        const int k0 = kt * 16 + khalf * 8;
        #pragma unroll
        for (int mt = 0; mt < 2; ++mt) {
            const int m = mt * 32 + col;
            const half8 ah = *(const half8*)&KHhi[m][k0];
            const half8 al = *(const half8*)&KHlo[m][k0];
            accK[mt] = __builtin_amdgcn_mfma_f32_32x32x16_f16(al, bh[kt & 1], accK[mt], 0, 0, 0);
            accK[mt] = __builtin_amdgcn_mfma_f32_32x32x16_f16(ah, bl[kt & 1], accK[mt], 0, 0, 0);
            accK[mt] = __builtin_amdgcn_mfma_f32_32x32x16_f16(ah, bh[kt & 1], accK[mt], 0, 0, 0);
        }
        if (DO_E) egroup<IS_EQ>(kt, accE, EHhi, EHlo, bias, khalf, ncol);  // VALU fills MFMA shadow
        if (kt < 6) { bh[kt & 1] = nbh; bl[kt & 1] = nbl; }
    }
}

// Final layer (128 -> 1) for one set: thread t reduces k-quarter (t&3) of row t>>2.
template<bool IS_EQ>
__device__ __forceinline__ void final_layer(const _Float16 (*Fhi)[HS],
                                            const _Float16 (*Flo)[HS],
                                            const float* __restrict__ W4, float b4v,
                                            float* __restrict__ out, int out_base,
                                            int tid)
{
    const int lane = tid & 63;
    const int w = tid >> 6;
    const int m = tid >> 2;
    const int q = tid & 3;
    float dot = 0.f;
    #pragma unroll
    for (int g = 0; g < 4; ++g) {
        const int f = 32 * q + 8 * g;
        const half8 hh = *(const half8*)&Fhi[m][f];
        const half8 hl = *(const half8*)&Flo[m][f];
        const float4 wa = *(const float4*)&W4[f];
        const float4 wb = *(const float4*)&W4[f + 4];
        dot = fmaf((float)hh[0] + (float)hl[0], wa.x, dot);
        dot = fmaf((float)hh[1] + (float)hl[1], wa.y, dot);
        dot = fmaf((float)hh[2] + (float)hl[2], wa.z, dot);
        dot = fmaf((float)hh[3] + (float)hl[3], wa.w, dot);
        dot = fmaf((float)hh[4] + (float)hl[4], wb.x, dot);
        dot = fmaf((float)hh[5] + (float)hl[5], wb.y, dot);
        dot = fmaf((float)hh[6] + (float)hl[6], wb.z, dot);
        dot = fmaf((float)hh[7] + (float)hl[7], wb.w, dot);
    }
    dot += __shfl_xor(dot, 1);
    dot += __shfl_xor(dot, 2);   // full row-dot at all 4 lanes of the row

    if (IS_EQ) {
        // wave w holds rows [16w,16w+16) = points [4w,4w+4); lane = 16p' + 4c + q
        const float uu   = __shfl(dot, (lane & 48) + 0)  + b4v;
        const float utv  = __shfl(dot, (lane & 48) + 4);
        const float uxv  = __shfl(dot, (lane & 48) + 8);
        const float uxxv = __shfl(dot, (lane & 48) + 12);
        if ((lane & 15) == 0)
            out[out_base + 4 * w + (lane >> 4)] = fmaf(uu, uxv, utv) - NU_F * uxxv;
    } else {
        if (q == 0)
            out[out_base + m] = dot + b4v;
    }
}

// ---------------------------------------------------------------------------
// Blocks 0..4095: equation, 2 sets x 16 pts (each set M=64 rows, m=4p+channel).
// Blocks 4096..4159: init/bound, 2 sets x 64 pts (m = p).
// Software pipeline: phase i runs K-loop(set X, layer l) interleaved with
// epilogue(set Y, layer l') so MFMA and VALU pipes are busy simultaneously.
// ---------------------------------------------------------------------------
__launch_bounds__(256, 2)
__global__ void pinn_kernel(const float* __restrict__ tx_eq,
                            const float* __restrict__ tx_init,
                            const float* __restrict__ tx_bnd,
                            const float* __restrict__ W0, const float* __restrict__ b0,
                            const float* __restrict__ b1, const float* __restrict__ b2,
                            const float* __restrict__ b3,
                            const float* __restrict__ W4, const float* __restrict__ b4,
                            const _Float16* __restrict__ wt,
                            float* __restrict__ out)
{
    __shared__ _Float16 Hhi[2][64][HS];   // 34.8 KB
    __shared__ _Float16 Hlo[2][64][HS];   // 34.8 KB

    const int tid   = threadIdx.x;
    const int blk   = blockIdx.x;
    const bool is_eq = (blk < 4096);
    const int w     = tid >> 6;
    const int lane  = tid & 63;
    const int col   = lane & 31;
    const int khalf = lane >> 5;
    const int ncol  = 32 * w + col;

    // ---- input layer (K=2, pointwise, fp32), both sets ----
    if (is_eq) {
        const int p  = tid >> 4;                 // 0..15
        const int f0 = (tid & 15) * 8;
        #pragma unroll
        for (int s = 0; s < 2; ++s) {
            const float tv = tx_eq[blk * 64 + (s * 16 + p) * 2];
            const float xv = tx_eq[blk * 64 + (s * 16 + p) * 2 + 1];
            float vch[4][8];
            #pragma unroll
            for (int j = 0; j < 8; ++j) {
                const int f = f0 + j;
                const float w0v = W0[f];
                const float w1v = W0[128 + f];
                const float z = fmaf(tv, w0v, fmaf(xv, w1v, b0[f]));
                const float a = fast_tanh(z);
                const float sd = 1.f - a * a;
                vch[0][j] = a;
                vch[1][j] = sd * w0v;
                vch[2][j] = sd * w1v;
                vch[3][j] = -2.f * a * sd * w1v * w1v;
            }
            const int m0 = 4 * p;
            #pragma unroll
            for (int c = 0; c < 4; ++c) {
                half8 hh, hl;
                #pragma unroll
                for (int j = 0; j < 8; ++j) {
                    const float v = vch[c][j];
                    const _Float16 hi = (_Float16)v;
                    hh[j] = hi;
                    hl[j] = (_Float16)(v - (float)hi);
                }
                *(half8*)&Hhi[s][m0 + c][f0] = hh;
                *(half8*)&Hlo[s][m0 + c][f0] = hl;
            }
        }
    } else {
        const int p  = tid >> 2;                 // 0..63 == row m
        const int f0 = (tid & 3) * 32;
        #pragma unroll
        for (int s = 0; s < 2; ++s) {
            const int gp = (blk - 4096) * 128 + s * 64 + p;
            const float* src = (gp < 4096) ? tx_init : tx_bnd;
            const int idx = (gp < 4096) ? gp : gp - 4096;
            const float tv = src[2 * idx];
            const float xv = src[2 * idx + 1];
            #pragma unroll
            for (int g = 0; g < 4; ++g) {
                half8 hh, hl;
                #pragma unroll
                for (int j = 0; j < 8; ++j) {
                    const int f = f0 + 8 * g + j;
                    const float v = fast_tanh(fmaf(tv, W0[f], fmaf(xv, W0[128 + f], b0[f])));
                    const _Float16 hi = (_Float16)v;
                    hh[j] = hi;
                    hl[j] = (_Float16)(v - (float)hi);
                }
                *(half8*)&Hhi[s][p][f0 + 8 * g] = hh;
                *(half8*)&Hlo[s][p][f0 + 8 * g] = hl;
            }
        }
    }
    __syncthreads();

    const float biasv0 = b1[ncol];
    const float biasv1 = b2[ncol];
    const float biasv2 = b3[ncol];
    const float b4v = b4[0];

    const int wofs = ncol * 16 + khalf * 8;
    const _Float16* p0 = wt + 0 * 16384 + wofs;
    const _Float16* p1 = wt + 1 * 16384 + wofs;
    const _Float16* p2 = wt + 2 * 16384 + wofs;

    f32x16 accA[2], accB[2];

    if (is_eq) {
        kphase<true , false>(p0, p0 + 49152, Hhi[0], Hlo[0], accA, accA, Hhi[1], Hlo[1], 0.f,    col, khalf, ncol);
        __syncthreads();
        kphase<true , true >(p0, p0 + 49152, Hhi[1], Hlo[1], accB, accA, Hhi[0], Hlo[0], biasv0, col, khalf, ncol);
        __syncthreads();
        kphase<true , true >(p1, p1 + 49152, Hhi[0], Hlo[0], accA, accB, Hhi[1], Hlo[1], biasv0, col, khalf, ncol);
        __syncthreads();
        kphase<true , true >(p1, p1 + 49152, Hhi[1], Hlo[1], accB, accA, Hhi[0], Hlo[0], biasv1, col, khalf, ncol);
        __syncthreads();
        kphase<true , true >(p2, p2 + 49152, Hhi[0], Hlo[0], accA, accB, Hhi[1], Hlo[1], biasv1, col, khalf, ncol);
        __syncthreads();
        kphase<true , true >(p2, p2 + 49152, Hhi[1], Hlo[1], accB, accA, Hhi[0], Hlo[0], biasv2, col, khalf, ncol);
        __syncthreads();
        #pragma unroll
        for (int g = 0; g < 8; ++g)
            egroup<true>(g, accB, Hhi[1], Hlo[1], biasv2, khalf, ncol);
        final_layer<true>(Hhi[0], Hlo[0], W4, b4v, out, blk * 32, tid);
        __syncthreads();
        final_layer<true>(Hhi[1], Hlo[1], W4, b4v, out, blk * 32 + 16, tid);
    } else {
        kphase<false, false>(p0, p0 + 49152, Hhi[0], Hlo[0], accA, accA, Hhi[1], Hlo[1], 0.f,    col, khalf, ncol);
        __syncthreads();
        kphase<false, true >(p0, p0 + 49152, Hhi[1], Hlo[1], accB, accA, Hhi[0], Hlo[0], biasv0, col, khalf, ncol);
        __syncthreads();
        kphase<false, true >(p1, p1 + 49152, Hhi[0], Hlo[0], accA, accB, Hhi[1], Hlo[1], biasv0, col, khalf, ncol);
        __syncthreads();
        kphase<false, true >(p1, p1 + 49152, Hhi[1], Hlo[1], accB, accA, Hhi[0], Hlo[0], biasv1, col, khalf, ncol);
        __syncthreads();
        kphase<false, true >(p2, p2 + 49152, Hhi[0], Hlo[0], accA, accB, Hhi[1], Hlo[1], biasv1, col, khalf, ncol);
        __syncthreads();
        kphase<false, true >(p2, p2 + 49152, Hhi[1], Hlo[1], accB, accA, Hhi[0], Hlo[0], biasv2, col, khalf, ncol);
        __syncthreads();
        #pragma unroll
        for (int g = 0; g < 8; ++g)
            egroup<false>(g, accB, Hhi[1], Hlo[1], biasv2, khalf, ncol);
        const int ob = 131072 + (blk - 4096) * 128;
        final_layer<false>(Hhi[0], Hlo[0], W4, b4v, out, ob, tid);
        __syncthreads();
        final_layer<false>(Hhi[1], Hlo[1], W4, b4v, out, ob + 64, tid);
    }
}

extern "C" void kernel_launch(void* const* d_in, const int* in_sizes, int n_in,
                              void* d_out, int out_size, void* d_ws, size_t ws_size,
                              hipStream_t stream)
{
    const float* tx_eq   = (const float*)d_in[0];
    const float* tx_init = (const float*)d_in[1];
    const float* tx_bnd  = (const float*)d_in[2];
    const float* W0 = (const float*)d_in[3];
    const float* b0 = (const float*)d_in[4];
    const float* W1 = (const float*)d_in[5];
    const float* b1 = (const float*)d_in[6];
    const float* W2 = (const float*)d_in[7];
    const float* b2 = (const float*)d_in[8];
    const float* W3 = (const float*)d_in[9];
    const float* b3 = (const float*)d_in[10];
    const float* W4 = (const float*)d_in[11];
    const float* b4 = (const float*)d_in[12];
    float* out = (float*)d_out;
    _Float16* wt = (_Float16*)d_ws;   // needs 196608 B

    hipLaunchKernelGGL(prep_kernel, dim3(192), dim3(256), 0, stream, W1, W2, W3, wt);
    // 4096 eq blocks (2x16 pts) + 64 ib blocks (2x64 pts)
    hipLaunchKernelGGL(pinn_kernel, dim3(4160), dim3(256), 0, stream,
                       tx_eq, tx_init, tx_bnd, W0, b0, b1, b2, b3, W4, b4,
                       (const _Float16*)wt, out);
}

// Round 8
// 216.245 us; speedup vs baseline: 1.3316x; 1.3316x over previous
//
#include <hip/hip_runtime.h>
#include <math.h>

#define NU_F 0.0031830988618379067f
#define HS 136   // halves per H row: 17*8 -> 16B-aligned, odd 16B-stride = bank-balanced

typedef __attribute__((ext_vector_type(8))) _Float16 half8;
typedef __attribute__((ext_vector_type(16))) float f32x16;

__device__ __forceinline__ float fast_tanh(float x) {
    const float e = __expf(2.f * x);
    return 1.f - 2.f / (e + 1.f);
}

// ---------------------------------------------------------------------------
// Weight prep: W[l][k][n] fp32 -> k-tiled fp16 hi/lo:
//   idx = l*16384 + (k>>4)*2048 + n*16 + (k&15)
// so a wave's per-kt B-read (n-contiguous, 16 halves each) is one 1KB block.
// B keeps the hi+lo split (W at fp32 accuracy); A (activations) is fp16-only.
// ---------------------------------------------------------------------------
__global__ void prep_kernel(const float* __restrict__ W1,
                            const float* __restrict__ W2,
                            const float* __restrict__ W3,
                            _Float16* __restrict__ ws)
{
    const int g = blockIdx.x * 256 + threadIdx.x;   // 0..49151
    const int l = g >> 14;
    const int r = g & 16383;
    const int n = r & 127;
    const int k = r >> 7;
    const float* W = (l == 0) ? W1 : (l == 1) ? W2 : W3;
    const float w = W[k * 128 + n];
    const _Float16 hi = (_Float16)w;
    const _Float16 lo = (_Float16)(w - (float)hi);
    const int idx = l * 16384 + (k >> 4) * 2048 + n * 16 + (k & 15);
    ws[idx]         = hi;
    ws[49152 + idx] = lo;
}

// ---------------------------------------------------------------------------
// Blocks 0..8191: equation, 16 pts (M=64 rows, m = 4p + channel).
// Blocks 8192..8319: init/bound forward-only, 64 pts (m = p).
// Wave w computes cols [32w,32w+32) for all 64 rows (mt=0,1).
// Per (kt,mt): 2 MFMAs (ah*bl + ah*bh) -> W fp32-exact, activations fp16.
// H single fp16 buffer (17.4 KB) -> 8 blocks/CU: overlap comes from TLP.
// ---------------------------------------------------------------------------
__launch_bounds__(256, 8)
__global__ void pinn_kernel(const float* __restrict__ tx_eq,
                            const float* __restrict__ tx_init,
                            const float* __restrict__ tx_bnd,
                            const float* __restrict__ W0, const float* __restrict__ b0,
                            const float* __restrict__ b1, const float* __restrict__ b2,
                            const float* __restrict__ b3,
                            const float* __restrict__ W4, const float* __restrict__ b4,
                            const _Float16* __restrict__ wt,
                            float* __restrict__ out)
{
    __shared__ _Float16 Hh[64][HS];   // 17.4 KB, in-place across layers

    const int tid   = threadIdx.x;
    const int blk   = blockIdx.x;
    const bool is_eq = (blk < 8192);
    const int w     = tid >> 6;
    const int lane  = tid & 63;
    const int col   = lane & 31;
    const int khalf = lane >> 5;
    const int ncol  = 32 * w + col;

    // ---- input layer (K=2, pointwise, fp32) ----
    if (is_eq) {
        const int p  = tid >> 4;                 // 0..15
        const int f0 = (tid & 15) * 8;
        const float tv = tx_eq[blk * 32 + 2 * p];
        const float xv = tx_eq[blk * 32 + 2 * p + 1];
        float vch[4][8];
        #pragma unroll
        for (int j = 0; j < 8; ++j) {
            const int f = f0 + j;
            const float w0v = W0[f];             // dz/dt
            const float w1v = W0[128 + f];       // dz/dx
            const float z = fmaf(tv, w0v, fmaf(xv, w1v, b0[f]));
            const float a = fast_tanh(z);
            const float s = 1.f - a * a;
            vch[0][j] = a;
            vch[1][j] = s * w0v;
            vch[2][j] = s * w1v;
            vch[3][j] = -2.f * a * s * w1v * w1v;
        }
        const int m0 = 4 * p;
        #pragma unroll
        for (int c = 0; c < 4; ++c) {
            half8 hh;
            #pragma unroll
            for (int j = 0; j < 8; ++j) hh[j] = (_Float16)vch[c][j];
            *(half8*)&Hh[m0 + c][f0] = hh;
        }
    } else {
        const int p  = tid >> 2;                 // 0..63 == row m
        const int f0 = (tid & 3) * 32;
        const int gp = (blk - 8192) * 64 + p;
        const float* src = (gp < 4096) ? tx_init : tx_bnd;
        const int idx = (gp < 4096) ? gp : gp - 4096;
        const float tv = src[2 * idx];
        const float xv = src[2 * idx + 1];
        #pragma unroll
        for (int g = 0; g < 4; ++g) {
            half8 hh;
            #pragma unroll
            for (int j = 0; j < 8; ++j) {
                const int f = f0 + 8 * g + j;
                hh[j] = (_Float16)fast_tanh(fmaf(tv, W0[f], fmaf(xv, W0[128 + f], b0[f])));
            }
            *(half8*)&Hh[p][f0 + 8 * g] = hh;
        }
    }
    __syncthreads();

    const float* barr[3] = {b1, b2, b3};

    #pragma unroll 1
    for (int layer = 0; layer < 3; ++layer) {
        const _Float16* __restrict__ ph = wt + layer * 16384 + ncol * 16 + khalf * 8;
        const _Float16* __restrict__ pl = ph + 49152;
        const float bias = barr[layer][ncol];

        f32x16 acc[2];
        #pragma unroll
        for (int mt = 0; mt < 2; ++mt)
            #pragma unroll
            for (int e = 0; e < 16; ++e) acc[mt][e] = 0.f;

        // rolling distance-2 B prefetch (each load = coalesced 1KB/wave)
        half8 bh[2], bl[2];
        bh[0] = *(const half8*)(ph);         bl[0] = *(const half8*)(pl);
        bh[1] = *(const half8*)(ph + 2048);  bl[1] = *(const half8*)(pl + 2048);

        #pragma unroll
        for (int kt = 0; kt < 8; ++kt) {
            half8 nbh, nbl;
            if (kt < 6) {
                nbh = *(const half8*)(ph + (kt + 2) * 2048);
                nbl = *(const half8*)(pl + (kt + 2) * 2048);
            }
            const int k0 = kt * 16 + khalf * 8;
            #pragma unroll
            for (int mt = 0; mt < 2; ++mt) {
                const half8 ah = *(const half8*)&Hh[mt * 32 + col][k0];
                acc[mt] = __builtin_amdgcn_mfma_f32_32x32x16_f16(ah, bl[kt & 1], acc[mt], 0, 0, 0);
                acc[mt] = __builtin_amdgcn_mfma_f32_32x32x16_f16(ah, bh[kt & 1], acc[mt], 0, 0, 0);
            }
            if (kt < 6) { bh[kt & 1] = nbh; bl[kt & 1] = nbl; }
        }
        __syncthreads();   // all reads of H done -> in-place overwrite safe

        // epilogue: reg group 4g..4g+3 = rows mt*32 + 8g + 4*khalf + {0..3};
        // eq: rows = {u,ut,ux,uxx} of one point -> chain rule in registers.
        #pragma unroll
        for (int mt = 0; mt < 2; ++mt)
            #pragma unroll
            for (int g = 0; g < 4; ++g) {
                const int mrow0 = mt * 32 + 8 * g + 4 * khalf;
                const float A0 = acc[mt][4 * g + 0];
                const float A1 = acc[mt][4 * g + 1];
                const float A2 = acc[mt][4 * g + 2];
                const float A3 = acc[mt][4 * g + 3];
                float h[4];
                if (is_eq) {
                    const float a = fast_tanh(A0 + bias);
                    const float s = 1.f - a * a;
                    h[0] = a;
                    h[1] = s * A1;
                    h[2] = s * A2;
                    h[3] = fmaf(s, A3, -2.f * a * s * A2 * A2);
                } else {
                    h[0] = fast_tanh(A0 + bias);
                    h[1] = fast_tanh(A1 + bias);
                    h[2] = fast_tanh(A2 + bias);
                    h[3] = fast_tanh(A3 + bias);
                }
                #pragma unroll
                for (int c = 0; c < 4; ++c)
                    Hh[mrow0 + c][ncol] = (_Float16)h[c];
            }
        __syncthreads();
    }

    // ---- final layer (128 -> 1): thread t reduces k-quarter (t&3) of row t>>2
    {
        const float b4v = b4[0];
        const int m = tid >> 2;
        const int q = tid & 3;
        float dot = 0.f;
        #pragma unroll
        for (int g = 0; g < 4; ++g) {
            const int f = 32 * q + 8 * g;
            const half8 hh = *(const half8*)&Hh[m][f];
            const float4 wa = *(const float4*)&W4[f];
            const float4 wb = *(const float4*)&W4[f + 4];
            dot = fmaf((float)hh[0], wa.x, dot);
            dot = fmaf((float)hh[1], wa.y, dot);
            dot = fmaf((float)hh[2], wa.z, dot);
            dot = fmaf((float)hh[3], wa.w, dot);
            dot = fmaf((float)hh[4], wb.x, dot);
            dot = fmaf((float)hh[5], wb.y, dot);
            dot = fmaf((float)hh[6], wb.z, dot);
            dot = fmaf((float)hh[7], wb.w, dot);
        }
        dot += __shfl_xor(dot, 1);   // reduce across the 4 k-quarters
        dot += __shfl_xor(dot, 2);   // full row-dot at all 4 lanes of the row

        if (is_eq) {
            // wave w holds rows [16w,16w+16) = points [4w,4w+4); lane = 16p' + 4c + q
            const float uu   = __shfl(dot, (lane & 48) + 0)  + b4v;
            const float utv  = __shfl(dot, (lane & 48) + 4);
            const float uxv  = __shfl(dot, (lane & 48) + 8);
            const float uxxv = __shfl(dot, (lane & 48) + 12);
            if ((lane & 15) == 0)
                out[blk * 16 + 4 * w + (lane >> 4)] = fmaf(uu, uxv, utv) - NU_F * uxxv;
        } else {
            if (q == 0)
                out[131072 + (blk - 8192) * 64 + m] = dot + b4v;
        }
    }
}

extern "C" void kernel_launch(void* const* d_in, const int* in_sizes, int n_in,
                              void* d_out, int out_size, void* d_ws, size_t ws_size,
                              hipStream_t stream)
{
    const float* tx_eq   = (const float*)d_in[0];
    const float* tx_init = (const float*)d_in[1];
    const float* tx_bnd  = (const float*)d_in[2];
    const float* W0 = (const float*)d_in[3];
    const float* b0 = (const float*)d_in[4];
    const float* W1 = (const float*)d_in[5];
    const float* b1 = (const float*)d_in[6];
    const float* W2 = (const float*)d_in[7];
    const float* b2 = (const float*)d_in[8];
    const float* W3 = (const float*)d_in[9];
    const float* b3 = (const float*)d_in[10];
    const float* W4 = (const float*)d_in[11];
    const float* b4 = (const float*)d_in[12];
    float* out = (float*)d_out;
    _Float16* wt = (_Float16*)d_ws;   // needs 196608 B

    hipLaunchKernelGGL(prep_kernel, dim3(192), dim3(256), 0, stream, W1, W2, W3, wt);
    // 8192 eq blocks (16 pts) + 128 ib blocks (64 pts)
    hipLaunchKernelGGL(pinn_kernel, dim3(8320), dim3(256), 0, stream,
                       tx_eq, tx_init, tx_bnd, W0, b0, b1, b2, b3, W4, b4,
                       (const _Float16*)wt, out);
}